// Round 8
// baseline (144.211 us; speedup 1.0000x reference)
//
#include <hip/hip_runtime.h>

// Flat cell-parallel deformable-conv net, r7 codegen recipe transplanted.
// cg = blockIdx*256+tid maps to (img, cell): 100% lane packing
// (B*196 = 3136*256 exactly for B=4096) vs r7's 196/256 = 76.6%.
// r7 recipe kept verbatim: weights staged to LDS (broadcast ds_read,
// SGPR file stays small), direct xs[int] indexing, k-outer/p-inner
// acc[4][8], factored bilinear, no __launch_bounds__ min-waves.
// New vs failed r3-r6 flats: no per-lane magic division (slot via two
// compares off block-uniform img_base), per-wave segmented butterfly +
// direct atomicAdd (r4/r5's 5MB WRITE_SIZE == atomic line writebacks
// ~= 0.8us HBM, not a real cost).

#define HH 28
#define WW 28
#define WP 30
#define NPOS 784
#define NPOOL 1568
#define CELLS 196

__global__ __launch_bounds__(256) void deform_net_kernel(
    const float* __restrict__ x,       // (B,1,28,28)
    const float* __restrict__ w_off,   // (18,1,3,3)
    const float* __restrict__ b_off,   // (18,)
    const float* __restrict__ w_conv,  // (8,1,3,3)
    const float* __restrict__ w_fc,    // (10,1568)
    const float* __restrict__ b_fc,    // (10,)
    float* __restrict__ out,           // (B,10), pre-zeroed
    int B)
{
    __shared__ float xs[3 * 900];      // 3 padded images, 10.8 KB
    __shared__ float wo_s[162];
    __shared__ float bo_s[18];
    __shared__ float wc_s[72];

    const int tid      = threadIdx.x;
    const int cell0    = blockIdx.x << 8;           // first global cell
    const int img_base = cell0 / CELLS;             // block-uniform
    const int base_lc  = cell0 - img_base * CELLS;  // 0..195

    if (tid < 162) wo_s[tid] = w_off[tid];
    if (tid < 18)  bo_s[tid] = b_off[tid];
    if (tid < 72)  wc_s[tid] = w_conv[tid];

    // Stage 3 zero-padded 30x30 images.
    for (int i = tid; i < 2700; i += 256) {
        int s = i / 900;
        int j = i - s * 900;
        int img = img_base + s;
        float v = 0.f;
        if (img < B) {
            int r = j / WP, c = j - r * WP;
            if (r >= 1 && r <= HH && c >= 1 && c <= WW)
                v = x[(size_t)img * NPOS + (r - 1) * WW + (c - 1)];
        }
        xs[i] = v;
    }
    __syncthreads();

    // Local-cell -> (slot, cell) without division: lc in [0, 451).
    const int lc   = base_lc + tid;
    const int slot = (lc >= 2 * CELLS) ? 2 : (lc >= CELLS ? 1 : 0);
    const int cell = lc - slot * CELLS;
    const int xb0  = slot * 900;
    const bool act = (cell0 + tid) < B * CELLS;

    float fc[10];
    #pragma unroll
    for (int c = 0; c < 10; c++) fc[c] = 0.f;

    if (act) {
        const int ph = cell / 14, pw = cell % 14;
        const int h0 = 2 * ph, w0 = 2 * pw;

        // 4x4 padded neighborhood covering the 4 positions' 3x3 taps.
        float nb[16];
        #pragma unroll
        for (int i = 0; i < 4; i++)
            #pragma unroll
            for (int j = 0; j < 4; j++)
                nb[i * 4 + j] = xs[xb0 + (h0 + i) * WP + (w0 + j)];

        float acc[4][8];
        #pragma unroll
        for (int p = 0; p < 4; p++)
            #pragma unroll
            for (int o = 0; o < 8; o++) acc[p][o] = 0.f;

        #pragma unroll
        for (int k = 0; k < 9; k++) {          // deform tap
            const int kx = k / 3, ky = k % 3;
            #pragma unroll
            for (int p = 0; p < 4; p++) {      // position within pool cell
                const int dh = p >> 1, dw = p & 1;

                float offx = bo_s[k], offy = bo_s[k + 9];
                #pragma unroll
                for (int t = 0; t < 9; t++) {
                    float nv = nb[(dh + t / 3) * 4 + (dw + t % 3)];
                    offx = fmaf(wo_s[k * 9 + t],       nv, offx);
                    offy = fmaf(wo_s[(k + 9) * 9 + t], nv, offy);
                }

                float p_x = (float)(h0 + dh + kx) + offx;
                float p_y = (float)(w0 + dw + ky) + offy;

                float q0x = floorf(p_x), q0y = floorf(p_y);
                float qltx = fminf(fmaxf(q0x,       0.f), 29.f);
                float qlty = fminf(fmaxf(q0y,       0.f), 29.f);
                float qrbx = fminf(fmaxf(q0x + 1.f, 0.f), 29.f);
                float qrby = fminf(fmaxf(q0y + 1.f, 0.f), 29.f);
                float px   = fminf(fmaxf(p_x,       0.f), 29.f);
                float py   = fminf(fmaxf(p_y,       0.f), 29.f);

                float gltx = 1.f + (qltx - px);
                float glty = 1.f + (qlty - py);
                float grbx = 1.f - (qrbx - px);
                float grby = 1.f - (qrby - py);

                int ilx = (int)qltx, ily = (int)qlty;
                int irx = (int)qrbx, iry = (int)qrby;

                float xlt = xs[xb0 + ilx * WP + ily];
                float xrb = xs[xb0 + irx * WP + iry];
                float xlb = xs[xb0 + ilx * WP + iry];
                float xrt = xs[xb0 + irx * WP + ily];

                float s = gltx * (glty * xlt + grby * xlb)
                        + grbx * (glty * xrt + grby * xrb);

                #pragma unroll
                for (int o = 0; o < 8; o++)
                    acc[p][o] = fmaf(wc_s[o * 9 + k], s, acc[p][o]);
            }
        }

        // relu + 2x2 maxpool + FC partials.
        #pragma unroll
        for (int o = 0; o < 8; o++) {
            float m = fmaxf(fmaxf(acc[0][o], acc[1][o]),
                            fmaxf(acc[2][o], acc[3][o]));
            m = fmaxf(m, 0.f);
            const float* wrow = w_fc + o * CELLS + cell;
            #pragma unroll
            for (int c = 0; c < 10; c++)
                fc[c] = fmaf(m, wrow[c * NPOOL], fc[c]);
        }
        if (cell == 0) {          // exactly one cell-0 thread per image
            #pragma unroll
            for (int c = 0; c < 10; c++) fc[c] += b_fc[c];
        }
    }

    // Per-wave segmented butterfly (wave spans <=2 images), lane 0 atomics.
    const int lane = tid & 63;
    const int wfl  = base_lc + (tid & ~63);        // wave's first local cell
    const int s0   = (wfl >= 2 * CELLS) ? 2 : (wfl >= CELLS ? 1 : 0);
    const int wll  = wfl + 63;                     // wave's last local cell
    const int s1   = (wll >= 2 * CELLS) ? 2 : (wll >= CELLS ? 1 : 0);
    const int img0 = img_base + s0;
    const int img1 = img_base + s1;

    if (s0 == s1) {
        #pragma unroll
        for (int c = 0; c < 10; c++) {
            float v = fc[c];
            #pragma unroll
            for (int sh = 32; sh > 0; sh >>= 1) v += __shfl_down(v, sh, 64);
            if (lane == 0 && img0 < B) atomicAdd(&out[img0 * 10 + c], v);
        }
    } else {
        const bool in0 = (slot == s0);
        #pragma unroll
        for (int c = 0; c < 10; c++) {
            float v0 = in0 ? fc[c] : 0.f;
            float v1 = fc[c] - v0;
            #pragma unroll
            for (int sh = 32; sh > 0; sh >>= 1) {
                v0 += __shfl_down(v0, sh, 64);
                v1 += __shfl_down(v1, sh, 64);
            }
            if (lane == 0) {
                if (img0 < B) atomicAdd(&out[img0 * 10 + c], v0);
                if (img1 < B) atomicAdd(&out[img1 * 10 + c], v1);
            }
        }
    }
}

extern "C" void kernel_launch(void* const* d_in, const int* in_sizes, int n_in,
                              void* d_out, int out_size, void* d_ws, size_t ws_size,
                              hipStream_t stream) {
    const float* x      = (const float*)d_in[0];
    const float* w_off  = (const float*)d_in[1];
    const float* b_off  = (const float*)d_in[2];
    const float* w_conv = (const float*)d_in[3];
    const float* w_fc   = (const float*)d_in[4];
    const float* b_fc   = (const float*)d_in[5];
    float* out = (float*)d_out;

    const int B = in_sizes[0] / NPOS;
    const int grid = (B * CELLS + 255) / 256;

    hipMemsetAsync(d_out, 0, (size_t)out_size * sizeof(float), stream);
    deform_net_kernel<<<grid, 256, 0, stream>>>(x, w_off, b_off, w_conv,
                                                w_fc, b_fc, out, B);
}

// Round 9
// 129.322 us; speedup vs baseline: 1.1151x; 1.1151x over previous
//
#include <hip/hip_runtime.h>

// Fused deformable-conv net — frozen r7 structure (69 us, 92% VALUBusy,
// 64 VGPR) + packed-fp32 math (VOP3P v_pk_fma_f32 etc.):
//  - offset conv computes (offx,offy) as one float2: 18 fma -> 9 pk_fma
//  - conv accumulate packs channel pairs: 8 fma -> 4 pk_fma
//  - weights staged interleaved as float2 in LDS (broadcast ds_read_b64)
// Frozen per r2-r8 evidence: 256-thr block, one image/block, if(tid<196),
// k-outer/p-inner, direct xs[int] indexing, LDS weights, no launch-bounds
// min, no atomics, shuffle+LDS reduce. Every restructure (r3,r4,r5,r6,r8)
// regressed on stalls; only in-body instruction cuts win.

#define HH 28
#define WW 28
#define WP 30
#define NPOS 784
#define NPOOL 1568
#define CELLS 196

typedef float f2 __attribute__((ext_vector_type(2)));

__global__ __launch_bounds__(256) void deform_net_kernel(
    const float* __restrict__ x,       // (B,1,28,28)
    const float* __restrict__ w_off,   // (18,1,3,3)
    const float* __restrict__ b_off,   // (18,)
    const float* __restrict__ w_conv,  // (8,1,3,3)
    const float* __restrict__ w_fc,    // (10,1568)
    const float* __restrict__ b_fc,    // (10,)
    float* __restrict__ out)           // (B,10)
{
    __shared__ float xs[900];          // padded image
    __shared__ f2 wo2_s[81];           // {w_off[k*9+t], w_off[81+k*9+t]}
    __shared__ f2 bo2_s[9];            // {b_off[k], b_off[k+9]}
    __shared__ f2 wc2_s[36];           // {w_conv[o2*18+k], w_conv[o2*18+9+k]}
    __shared__ float red[4][10];

    const int b   = blockIdx.x;
    const int tid = threadIdx.x;

    if (tid < 81) wo2_s[tid] = (f2){w_off[tid], w_off[tid + 81]};
    if (tid < 9)  bo2_s[tid] = (f2){b_off[tid], b_off[tid + 9]};
    if (tid < 36) {
        int o2 = tid / 9, k = tid - o2 * 9;
        wc2_s[tid] = (f2){w_conv[o2 * 18 + k], w_conv[o2 * 18 + 9 + k]};
    }

    // Stage zero-padded image into LDS.
    const float* xb = x + (size_t)b * NPOS;
    for (int i = tid; i < 900; i += 256) {
        int r = i / WP, c = i % WP;
        float v = 0.f;
        if (r >= 1 && r <= HH && c >= 1 && c <= WW)
            v = xb[(r - 1) * WW + (c - 1)];
        xs[i] = v;
    }
    __syncthreads();

    float fc[10];
    #pragma unroll
    for (int c = 0; c < 10; c++) fc[c] = 0.f;

    if (tid < CELLS) {
        const int ph = tid / 14, pw = tid % 14;   // pool cell coords
        const int h0 = 2 * ph, w0 = 2 * pw;       // top-left output position

        // 4x4 padded-image neighborhood covering all 4 positions' 3x3 taps.
        float nb[16];
        #pragma unroll
        for (int i = 0; i < 4; i++)
            #pragma unroll
            for (int j = 0; j < 4; j++)
                nb[i * 4 + j] = xs[(h0 + i) * WP + (w0 + j)];

        f2 acc2[4][4];                 // [pos][channel-pair]
        #pragma unroll
        for (int p = 0; p < 4; p++)
            #pragma unroll
            for (int o2 = 0; o2 < 4; o2++) acc2[p][o2] = (f2){0.f, 0.f};

        #pragma unroll
        for (int k = 0; k < 9; k++) {          // deform tap
            const int kx = k / 3, ky = k % 3;
            #pragma unroll
            for (int p = 0; p < 4; p++) {      // position within pool cell
                const int dh = p >> 1, dw = p & 1;

                // (offx, offy) as one packed pair: 9 pk_fma
                f2 off = bo2_s[k];
                #pragma unroll
                for (int t = 0; t < 9; t++) {
                    float nv = nb[(dh + t / 3) * 4 + (dw + t % 3)];
                    off += wo2_s[k * 9 + t] * (f2){nv, nv};
                }

                // sample coords in padded frame (packed add)
                f2 pxy = (f2){(float)(h0 + dh + kx), (float)(w0 + dw + ky)} + off;
                float p_x = pxy.x, p_y = pxy.y;

                float q0x = floorf(p_x), q0y = floorf(p_y);
                float qltx = fminf(fmaxf(q0x,       0.f), 29.f);
                float qlty = fminf(fmaxf(q0y,       0.f), 29.f);
                float qrbx = fminf(fmaxf(q0x + 1.f, 0.f), 29.f);
                float qrby = fminf(fmaxf(q0y + 1.f, 0.f), 29.f);
                float px   = fminf(fmaxf(p_x,       0.f), 29.f);
                float py   = fminf(fmaxf(p_y,       0.f), 29.f);

                float gltx = 1.f + (qltx - px);
                float glty = 1.f + (qlty - py);
                float grbx = 1.f - (qrbx - px);
                float grby = 1.f - (qrby - py);

                int ilx = (int)qltx, ily = (int)qlty;
                int irx = (int)qrbx, iry = (int)qrby;

                float xlt = xs[ilx * WP + ily];
                float xrb = xs[irx * WP + iry];
                float xlb = xs[ilx * WP + iry];
                float xrt = xs[irx * WP + ily];

                float s = gltx * (glty * xlt + grby * xlb)
                        + grbx * (glty * xrt + grby * xrb);

                // 8-channel accumulate as 4 packed fma
                f2 s2 = (f2){s, s};
                #pragma unroll
                for (int o2 = 0; o2 < 4; o2++)
                    acc2[p][o2] += wc2_s[o2 * 9 + k] * s2;
            }
        }

        // relu + 2x2 maxpool (per channel), then FC partial sums.
        #pragma unroll
        for (int o2 = 0; o2 < 4; o2++) {
            float mx = fmaxf(fmaxf(acc2[0][o2].x, acc2[1][o2].x),
                             fmaxf(acc2[2][o2].x, acc2[3][o2].x));
            float my = fmaxf(fmaxf(acc2[0][o2].y, acc2[1][o2].y),
                             fmaxf(acc2[2][o2].y, acc2[3][o2].y));
            mx = fmaxf(mx, 0.f);
            my = fmaxf(my, 0.f);
            const float* wrx = w_fc + (2 * o2)     * CELLS + tid;
            const float* wry = w_fc + (2 * o2 + 1) * CELLS + tid;
            #pragma unroll
            for (int c = 0; c < 10; c++) {
                fc[c] = fmaf(mx, wrx[c * NPOOL], fc[c]);
                fc[c] = fmaf(my, wry[c * NPOOL], fc[c]);
            }
        }
    }

    // Wave (64-lane) shuffle reduce, then cross-wave via LDS.
    #pragma unroll
    for (int c = 0; c < 10; c++) {
        #pragma unroll
        for (int sh = 32; sh > 0; sh >>= 1)
            fc[c] += __shfl_down(fc[c], sh, 64);
    }
    const int wave = tid >> 6, lane = tid & 63;
    if (lane == 0) {
        #pragma unroll
        for (int c = 0; c < 10; c++) red[wave][c] = fc[c];
    }
    __syncthreads();
    if (tid < 10)
        out[b * 10 + tid] = red[0][tid] + red[1][tid] + red[2][tid]
                          + red[3][tid] + b_fc[tid];
}

extern "C" void kernel_launch(void* const* d_in, const int* in_sizes, int n_in,
                              void* d_out, int out_size, void* d_ws, size_t ws_size,
                              hipStream_t stream) {
    const float* x      = (const float*)d_in[0];
    const float* w_off  = (const float*)d_in[1];
    const float* b_off  = (const float*)d_in[2];
    const float* w_conv = (const float*)d_in[3];
    const float* w_fc   = (const float*)d_in[4];
    const float* b_fc   = (const float*)d_in[5];
    float* out = (float*)d_out;

    const int B = in_sizes[0] / NPOS;
    deform_net_kernel<<<B, 256, 0, stream>>>(x, w_off, b_off, w_conv, w_fc, b_fc, out);
}

// Round 10
// 126.223 us; speedup vs baseline: 1.1425x; 1.0245x over previous
//
#include <hip/hip_runtime.h>

// Fused deformable-conv net — r7 structure (69 us, 92% VALUBusy) with one
// surgical change: per-k weight hoisting. The 28 weight scalars used by a
// deform tap k (18 w_off, 2 b_off, 8 w_conv) are k-invariant across the 4
// pool positions; r7 re-read them from LDS every (k,p) = 1008 ds_read
// issue slots/wave. Hoisting to k-scope registers cuts that to 252.
// Reverted r9's packed fp32: v_pk_fma_f32 is 2-pass on gfx950 (157.3 TF
// spec == scalar SIMD-32 rate, per m07) — density only, no throughput,
// and it halved the independent-chain count -> stalls.
// Frozen per r2-r9 evidence: 256-thr block, one image/block, if(tid<196),
// k-outer/p-inner acc[4][8], direct xs[int] indexing, LDS weights, no
// launch-bounds min, no atomics, shuffle+LDS reduce.

#define HH 28
#define WW 28
#define WP 30
#define NPOS 784
#define NPOOL 1568
#define CELLS 196

__global__ __launch_bounds__(256) void deform_net_kernel(
    const float* __restrict__ x,       // (B,1,28,28)
    const float* __restrict__ w_off,   // (18,1,3,3)
    const float* __restrict__ b_off,   // (18,)
    const float* __restrict__ w_conv,  // (8,1,3,3)
    const float* __restrict__ w_fc,    // (10,1568)
    const float* __restrict__ b_fc,    // (10,)
    float* __restrict__ out)           // (B,10)
{
    __shared__ float xs[900];          // padded image
    __shared__ float wo_s[162];        // w_off
    __shared__ float bo_s[18];         // b_off
    __shared__ float wc_s[72];         // w_conv
    __shared__ float red[4][10];

    const int b   = blockIdx.x;
    const int tid = threadIdx.x;

    if (tid < 162) wo_s[tid] = w_off[tid];
    if (tid < 18)  bo_s[tid] = b_off[tid];
    if (tid < 72)  wc_s[tid] = w_conv[tid];

    // Stage zero-padded image into LDS.
    const float* xb = x + (size_t)b * NPOS;
    for (int i = tid; i < 900; i += 256) {
        int r = i / WP, c = i % WP;
        float v = 0.f;
        if (r >= 1 && r <= HH && c >= 1 && c <= WW)
            v = xb[(r - 1) * WW + (c - 1)];
        xs[i] = v;
    }
    __syncthreads();

    float fc[10];
    #pragma unroll
    for (int c = 0; c < 10; c++) fc[c] = 0.f;

    if (tid < CELLS) {
        const int ph = tid / 14, pw = tid % 14;   // pool cell coords
        const int h0 = 2 * ph, w0 = 2 * pw;       // top-left output position

        // 4x4 padded-image neighborhood covering all 4 positions' 3x3 taps.
        float nb[16];
        #pragma unroll
        for (int i = 0; i < 4; i++)
            #pragma unroll
            for (int j = 0; j < 4; j++)
                nb[i * 4 + j] = xs[(h0 + i) * WP + (w0 + j)];

        float acc[4][8];
        #pragma unroll
        for (int p = 0; p < 4; p++)
            #pragma unroll
            for (int o = 0; o < 8; o++) acc[p][o] = 0.f;

        #pragma unroll
        for (int k = 0; k < 9; k++) {          // deform tap
            const int kx = k / 3, ky = k % 3;

            // --- k-scope weight hoist: 28 LDS reads, reused by 4 positions ---
            float wox[9], woy[9];
            #pragma unroll
            for (int t = 0; t < 9; t++) {
                wox[t] = wo_s[k * 9 + t];
                woy[t] = wo_s[(k + 9) * 9 + t];
            }
            const float bkx = bo_s[k], bky = bo_s[k + 9];
            float wck[8];
            #pragma unroll
            for (int o = 0; o < 8; o++) wck[o] = wc_s[o * 9 + k];

            #pragma unroll
            for (int p = 0; p < 4; p++) {      // position within pool cell
                const int dh = p >> 1, dw = p & 1;

                // offset channels k (x) and k+9 (y): 3x3 conv at (h0+dh, w0+dw)
                float offx = bkx, offy = bky;
                #pragma unroll
                for (int t = 0; t < 9; t++) {
                    float nv = nb[(dh + t / 3) * 4 + (dw + t % 3)];
                    offx = fmaf(wox[t], nv, offx);
                    offy = fmaf(woy[t], nv, offy);
                }

                // sample coords in padded frame: p0=(h+1,w+1), pn=(kx-1,ky-1)
                float p_x = (float)(h0 + dh + kx) + offx;
                float p_y = (float)(w0 + dw + ky) + offy;

                float q0x = floorf(p_x), q0y = floorf(p_y);
                float qltx = fminf(fmaxf(q0x,       0.f), 29.f);
                float qlty = fminf(fmaxf(q0y,       0.f), 29.f);
                float qrbx = fminf(fmaxf(q0x + 1.f, 0.f), 29.f);
                float qrby = fminf(fmaxf(q0y + 1.f, 0.f), 29.f);
                float px   = fminf(fmaxf(p_x,       0.f), 29.f);
                float py   = fminf(fmaxf(p_y,       0.f), 29.f);

                float gltx = 1.f + (qltx - px);
                float glty = 1.f + (qlty - py);
                float grbx = 1.f - (qrbx - px);
                float grby = 1.f - (qrby - py);

                int ilx = (int)qltx, ily = (int)qlty;
                int irx = (int)qrbx, iry = (int)qrby;

                float xlt = xs[ilx * WP + ily];
                float xrb = xs[irx * WP + iry];
                float xlb = xs[ilx * WP + iry];
                float xrt = xs[irx * WP + ily];

                // factored bilinear combine (same clip semantics)
                float s = gltx * (glty * xlt + grby * xlb)
                        + grbx * (glty * xrt + grby * xrb);

                #pragma unroll
                for (int o = 0; o < 8; o++)
                    acc[p][o] = fmaf(wck[o], s, acc[p][o]);
            }
        }

        // relu + 2x2 maxpool in registers, then FC partial sums.
        #pragma unroll
        for (int o = 0; o < 8; o++) {
            float m = fmaxf(fmaxf(acc[0][o], acc[1][o]),
                            fmaxf(acc[2][o], acc[3][o]));
            m = fmaxf(m, 0.f);
            const float* wrow = w_fc + o * CELLS + tid;  // flat idx o*196+cell
            #pragma unroll
            for (int c = 0; c < 10; c++)
                fc[c] = fmaf(m, wrow[c * NPOOL], fc[c]);
        }
    }

    // Wave (64-lane) shuffle reduce, then cross-wave via LDS.
    #pragma unroll
    for (int c = 0; c < 10; c++) {
        #pragma unroll
        for (int sh = 32; sh > 0; sh >>= 1)
            fc[c] += __shfl_down(fc[c], sh, 64);
    }
    const int wave = tid >> 6, lane = tid & 63;
    if (lane == 0) {
        #pragma unroll
        for (int c = 0; c < 10; c++) red[wave][c] = fc[c];
    }
    __syncthreads();
    if (tid < 10)
        out[b * 10 + tid] = red[0][tid] + red[1][tid] + red[2][tid]
                          + red[3][tid] + b_fc[tid];
}

extern "C" void kernel_launch(void* const* d_in, const int* in_sizes, int n_in,
                              void* d_out, int out_size, void* d_ws, size_t ws_size,
                              hipStream_t stream) {
    const float* x      = (const float*)d_in[0];
    const float* w_off  = (const float*)d_in[1];
    const float* b_off  = (const float*)d_in[2];
    const float* w_conv = (const float*)d_in[3];
    const float* w_fc   = (const float*)d_in[4];
    const float* b_fc   = (const float*)d_in[5];
    float* out = (float*)d_out;

    const int B = in_sizes[0] / NPOS;
    deform_net_kernel<<<B, 256, 0, stream>>>(x, w_off, b_off, w_conv, w_fc, b_fc, out);
}